// Round 13
// baseline (189.807 us; speedup 1.0000x reference)
//
#include <hip/hip_runtime.h>
#include <hip/hip_bf16.h>

typedef __hip_bfloat16 bf16;
typedef unsigned short ushort8v __attribute__((ext_vector_type(8)));
typedef short  s16x4  __attribute__((ext_vector_type(4)));
typedef short  bf16x8 __attribute__((ext_vector_type(8)));   // 8 bf16 (4 VGPRs)
typedef float  f32x4  __attribute__((ext_vector_type(4)));

#define HW 4096
#define IMG_W 64

__device__ __forceinline__ float bfbits2f(unsigned short u) {
    return __uint_as_float(((unsigned int)u) << 16);
}
__device__ __forceinline__ short f2bs(float f) {
    bf16 h = __float2bfloat16(f);
    return *reinterpret_cast<short*>(&h);
}

// async global->LDS, 16B per lane. LDS dest = wave-uniform base + lane*16;
// the GLOBAL source address is per-lane (m173 pattern).
__device__ __forceinline__ void gl_lds16(const void* g, void* s) {
    __builtin_amdgcn_global_load_lds(
        (const __attribute__((address_space(1))) unsigned int*)g,
        (__attribute__((address_space(3))) unsigned int*)s, 16, 0, 0);
}

// ---------------------------------------------------------------------------
// pack_input: concat(gar,cond) fp32 [512][4096] -> inp_t bf16 chunked
// [cc=16][pix=4096][32ch] (conv1 DMA layout) AND gar_t bf16 pixel-major
// [4096 px][256 ch] (warp_combine gather layout).
// ---------------------------------------------------------------------------
__device__ void pack_input_dev(const float* __restrict__ gar,
                               const float* __restrict__ cond,
                               short* __restrict__ outp,
                               short* __restrict__ gart, int bx2, float* tile)
{
    int bx = bx2 & 127;                // px tile (128)
    int by = bx2 >> 7;                 // ch tile (16) == cc chunk
    int tx = threadIdx.x & 31;
    int ty = threadIdx.x >> 5;
#pragma unroll
    for (int i = 0; i < 4; ++i) {
        int c = by * 32 + ty + i * 8;
        const float* src = (c < 256) ? (gar + (size_t)c * HW)
                                     : (cond + (size_t)(c - 256) * HW);
        tile[(ty + i * 8) * 33 + tx] = src[bx * 32 + tx];
    }
    __syncthreads();
#pragma unroll
    for (int i = 0; i < 4; ++i) {
        int p = bx * 32 + ty + i * 8;
        short v = f2bs(tile[tx * 33 + ty + i * 8]);
        outp[((size_t)by * 4096 + p) * 32 + tx] = v;
        if (by < 8)                    // gar channels only (block-uniform)
            gart[(size_t)p * 256 + by * 32 + tx] = v;
    }
}

// ---------------------------------------------------------------------------
// pack_w: W fp32 [G][CREAL][CIN][3][3] -> bf16 blocks.
// COAL layout (all convs): [g][nt][cc][tap 9][oc BN][q 4][8 ic] -> a wave's
// 64-lane weight-fragment load is one contiguous span; tap+1 prefetch at
// tap 8 rolls into the next cc's tap 0 by construction.
// BLKB = 9*4*BN*16 bytes.
// ---------------------------------------------------------------------------
template<int CIN, int CREAL, int BN, int NT, bool COAL>
__device__ void pack_w_dev(const float* __restrict__ wgt, char* __restrict__ wp,
                           int bx, short* sT)
{
    constexpr int NCC  = CIN / 32;
    constexpr int BLKB = 9 * 4 * BN * 16;

    const int t  = threadIdx.x;
    const int cc = bx % NCC;
    const int nt = (bx / NCC) % NT;
    const int g  = bx / (NT * NCC);

    for (int i = t; i < BLKB / 8; i += 256)
        reinterpret_cast<s16x4*>(sT)[i] = s16x4{0, 0, 0, 0};
    __syncthreads();

    int ocmax = CREAL - nt * BN; if (ocmax > BN) ocmax = BN;
    const size_t base = ((size_t)(g * CREAL + nt * BN) * CIN + cc * 32) * 9;
    for (int i = t; i < ocmax * 288; i += 256) {
        int oc = i / 288;
        int r  = i % 288;                      // ic*9 + tap
        int ic = r / 9, tap = r % 9;
        size_t idx;
        if (COAL) idx = (size_t)(((tap * BN + oc) * 4 + (ic >> 3)) * 8 + (ic & 7));
        else      idx = (size_t)(((tap * 4 + (ic >> 3)) * BN + oc) * 8 + (ic & 7));
        sT[idx] = f2bs(wgt[base + (size_t)oc * CIN * 9 + r]);
    }
    __syncthreads();

    const s16x4* src = reinterpret_cast<const s16x4*>(sT);
    s16x4* dst = reinterpret_cast<s16x4*>(wp + (size_t)bx * BLKB);
    for (int i = t; i < BLKB / 8; i += 256)
        dst[i] = src[i];
}

// All packing in one launch (block-range dispatch; branch is block-uniform).
__global__ __launch_bounds__(256)
void pack_all(const float* __restrict__ gar, const float* __restrict__ cond,
              const float* __restrict__ W1, const float* __restrict__ W2,
              const float* __restrict__ W3, const float* __restrict__ W4,
              short* inp_t, short* gar_t,
              char* W1p, char* W2p, char* W3p, char* W4p)
{
    __shared__ __align__(16) short sbuf[9 * 4 * 64 * 8];   // 36864 B
    int bx = blockIdx.x;
    if (bx < 256)      pack_w_dev<512, 128, 64, 2, true>(W1, W1p, bx,       sbuf);
    else if (bx < 288) pack_w_dev<128,  64, 64, 1, true>(W2, W2p, bx - 256, sbuf);
    else if (bx < 304) pack_w_dev< 64,  32, 32, 1, true>(W3, W3p, bx - 288, sbuf);
    else if (bx < 312) pack_w_dev< 32,  18, 32, 1, true>(W4, W4p, bx - 304, sbuf);
    else pack_input_dev(gar, cond, inp_t, gar_t, bx - 312, (float*)sbuf);
}

// ---------------------------------------------------------------------------
// conv1_p2: dual-stream register pipeline, full-K, 2 blocks/CU (512 x 256).
// Round-10 verified (48.5us). THIS ROUND: epilogue packs the 4 consecutive
// oc (reg 0-3) into one s16x4 8B store -> 8 stores/thread instead of 32.
// ---------------------------------------------------------------------------
__global__ __launch_bounds__(256, 2)
void conv1_p2(const short* __restrict__ inp, const char* __restrict__ wp,
              const float* __restrict__ bias, short* __restrict__ outp)
{
    __shared__ __align__(16) short sA[2][4][66][4][8];   // 33792 B

    const int b  = blockIdx.x;
    const int g  = b & 7;                     // XCD swizzle: group per XCD
    const int r_ = b >> 3;
    const int pt = r_ & 31;                   // 0..31
    const int nt = r_ >> 5;                   // oc 64-half (0-1)
    const int r0 = pt * 2;

    const int t    = threadIdx.x;
    const int wave = t >> 6, lane = t & 63;
    const int l15  = lane & 15, quad = lane >> 4;

    const int row_l = wave & 1;               // px row (0-1)
    const int ocw   = (wave >> 1) * 32;       // oc 32-group within nt

    // W1p layout [g][nt][cc 16][tap 9][oc 64][q 4][ic 8]
    const short* wb    = (const short*)wp + (size_t)(g * 2 + nt) * 16 * 18432;
    const short* wlane = wb + ((size_t)(ocw + l15) * 4 + quad) * 8;

    // staging: wave w stages halo row w (4 x 1KB DMA)
    auto stageDMA = [&](int cc, int buf) {
        const int gy = r0 - 1 + wave;
        if (gy >= 0 && gy < 64) {
            const short* src = inp + ((size_t)cc * 4096 + (size_t)gy * 64) * 32
                                   + (size_t)lane * 8;
#pragma unroll
            for (int c4 = 0; c4 < 4; ++c4)
                gl_lds16(src + c4 * 512, &sA[buf][wave][1 + c4 * 16][0][0]);
        }
    };

    f32x4 acc[2][4];
#pragma unroll
    for (int o = 0; o < 2; ++o)
#pragma unroll
        for (int f = 0; f < 4; ++f)
#pragma unroll
            for (int r = 0; r < 4; ++r) acc[o][f][r] = 0.f;

    // prologue: DMA(0) into buf0, zero x-pads (both bufs) + OOB rows
    stageDMA(0, 0);
    if (t < 64) {
        int buf = t >> 5, row = (t >> 3) & 3, q = (t >> 1) & 3;
        int col = (t & 1) ? 65 : 0;
        *reinterpret_cast<bf16x8*>(&sA[buf][row][col][q][0]) =
            bf16x8{0, 0, 0, 0, 0, 0, 0, 0};
    }
    if (r0 == 0 || r0 == 62) {
        int zr = (r0 == 0) ? 0 : 3;           // gy=-1 or gy=64: zero forever
        for (int i = t; i < 2 * 66 * 4; i += 256) {
            int buf = i / 264, rem = i % 264;
            *reinterpret_cast<bf16x8*>(&sA[buf][zr][rem >> 2][rem & 3][0]) =
                bf16x8{0, 0, 0, 0, 0, 0, 0, 0};
        }
    }

    // weight double-buffer (16 VGPR) + pF double-buffer (32 VGPR)
    bf16x8 w[2][2];
    bf16x8 pf[2][4];
#pragma unroll
    for (int o = 0; o < 2; ++o)               // cc0 tap0 weights -> w[0]
        w[0][o] = *reinterpret_cast<const bf16x8*>(wlane + o * 512);

    auto body = [&](int cc, int cur, int par) {
        const short* wcc = wlane + (size_t)cc * 18432;
        __syncthreads();                      // sA[cur] published (DMA drained)
        if (cc + 1 < 16) stageDMA(cc + 1, cur ^ 1);
        // prime tap0 pF
#pragma unroll
        for (int f = 0; f < 4; ++f)
            pf[0][f] = *reinterpret_cast<const bf16x8*>(
                &sA[cur][row_l][f * 16 + l15][quad][0]);
#pragma unroll
        for (int tap = 0; tap < 9; ++tap) {
            const int pb = tap & 1, pn = pb ^ 1;
            const int cb = (tap + par) & 1, nb = cb ^ 1;
            // prefetch next tap's pF (taps 0-7)
            if (tap < 8) {
                const int dy1 = (tap + 1) / 3, dx1 = (tap + 1) % 3;
#pragma unroll
                for (int f = 0; f < 4; ++f)
                    pf[pn][f] = *reinterpret_cast<const bf16x8*>(
                        &sA[cur][row_l + dy1][f * 16 + l15 + dx1][quad][0]);
            }
            // prefetch next tap's weights (tap8 -> next cc's tap0 by layout)
            const short* nsrc = wcc + (size_t)(tap + 1) * 2048;
#pragma unroll
            for (int o = 0; o < 2; ++o)
                w[nb][o] = *reinterpret_cast<const bf16x8*>(nsrc + o * 512);
            __builtin_amdgcn_sched_barrier(0);   // pin both streams pre-MFMA
#pragma unroll
            for (int o = 0; o < 2; ++o)
#pragma unroll
                for (int f = 0; f < 4; ++f)
                    acc[o][f] = __builtin_amdgcn_mfma_f32_16x16x32_bf16(
                        w[cb][o], pf[pb][f], acc[o][f], 0, 0, 0);
        }
    };

    for (int c2 = 0; c2 < 16; c2 += 2) {
        body(c2,     0, 0);
        body(c2 + 1, 1, 1);
    }

    // epilogue: bias + leaky -> bf16, out [pix][128]. m(oc)=quad*4+reg.
    // regs 0-3 are CONSECUTIVE oc -> one s16x4 (8B) store per (o,f).
    const int prow = r0 + row_l;
    const size_t pixbase = (size_t)g * 4096 + (size_t)prow * 64;
#pragma unroll
    for (int o = 0; o < 2; ++o) {
        const int ocb = nt * 64 + ocw + o * 16 + quad * 4;
        const float4 bv4 = *reinterpret_cast<const float4*>(bias + g * 128 + ocb);
        const float bvv[4] = {bv4.x, bv4.y, bv4.z, bv4.w};
#pragma unroll
        for (int f = 0; f < 4; ++f) {
            s16x4 pkt;
#pragma unroll
            for (int reg = 0; reg < 4; ++reg) {
                float v = acc[o][f][reg] + bvv[reg];
                v = v >= 0.f ? v : 0.1f * v;
                pkt[reg] = f2bs(v);
            }
            *reinterpret_cast<s16x4*>(
                outp + (pixbase + f * 16 + l15) * 128 + ocb) = pkt;
        }
    }
}

// ---------------------------------------------------------------------------
// conv2_ss: single-shot staging (round-12 verified, neutral vs per-cc dbuf
// -> kept for fewer barriers). THIS ROUND: packed s16x4 epilogue stores.
// 8 waves = 2 px-rows x 4 oc-16-groups; grid 256 x 512; 2 blocks/CU.
// ---------------------------------------------------------------------------
__global__ __launch_bounds__(512, 2)
void conv2_ss(const short* __restrict__ inp, const char* __restrict__ wp,
              const float* __restrict__ bias, short* __restrict__ outp)
{
    __shared__ __align__(16) short sA[4][4][66][4][8];   // 67584 B

    const int b  = blockIdx.x;
    const int g  = b & 7;
    const int pt = b >> 3;                    // 0..31
    const int r0 = pt * 2;

    const int t    = threadIdx.x;
    const int wave = t >> 6, lane = t & 63;
    const int l15  = lane & 15, quad = lane >> 4;

    const int row_l = wave & 1;               // px row (0-1)
    const int ocq   = wave >> 1;              // oc 16-group (0-3)

    // W2p layout [g][cc 4][tap 9][oc 64][q 4][ic 8]
    const short* wb    = (const short*)wp + (size_t)g * 4 * 18432;
    const short* wlane = wb + ((size_t)(ocq * 16 + l15) * 4 + quad) * 8;

    // ---- stage ALL 4 cc: 16 (cc,row) units; wave w -> units 2w, 2w+1 ----
#pragma unroll
    for (int s = 0; s < 2; ++s) {
        const int u   = wave * 2 + s;
        const int cc  = u >> 2, row = u & 3;
        const int gy  = r0 - 1 + row;
        if (gy >= 0 && gy < 64) {
            const short* rowb = inp + ((size_t)g * 4096 + (size_t)gy * 64) * 128
                                    + cc * 32 + (lane & 3) * 8;
#pragma unroll
            for (int i = 0; i < 4; ++i)
                gl_lds16(rowb + (size_t)(i * 16 + (lane >> 2)) * 128,
                         &sA[cc][row][1 + i * 16][0][0]);
        }
    }
    // x-pad zero: 4cc x 4row x {0,65} x 4q = 128 units
    if (t < 128) {
        int cc = t >> 5, row = (t >> 3) & 3, col = (t & 4) ? 65 : 0, q = t & 3;
        *reinterpret_cast<bf16x8*>(&sA[cc][row][col][q][0]) =
            bf16x8{0, 0, 0, 0, 0, 0, 0, 0};
    }
    if (r0 == 0 || r0 == 62) {
        int zr = (r0 == 0) ? 0 : 3;           // gy=-1 or gy=64 row: zeros
        for (int i = t; i < 4 * 264; i += 512) {
            int cc = i / 264, rem = i % 264;
            *reinterpret_cast<bf16x8*>(&sA[cc][zr][rem >> 2][rem & 3][0]) =
                bf16x8{0, 0, 0, 0, 0, 0, 0, 0};
        }
    }

    f32x4 acc[4];
#pragma unroll
    for (int f = 0; f < 4; ++f)
#pragma unroll
        for (int r = 0; r < 4; ++r) acc[f][r] = 0.f;

    bf16x8 w[2];
    bf16x8 pf[2][4];
    w[0] = *reinterpret_cast<const bf16x8*>(wlane);    // cc0 tap0 weights

    __syncthreads();   // the ONLY barrier: all staging drained & visible

    // prime cc0 tap0 pF
#pragma unroll
    for (int f = 0; f < 4; ++f)
        pf[0][f] = *reinterpret_cast<const bf16x8*>(
            &sA[0][row_l][f * 16 + l15][quad][0]);

#pragma unroll
    for (int cc = 0; cc < 4; ++cc) {
        const short* wcc = wlane + (size_t)cc * 18432;
#pragma unroll
        for (int tap = 0; tap < 9; ++tap) {
            const int pb = (cc + tap) & 1, pn = pb ^ 1;  // shared parity
            // prefetch next global tap's pF
            if (tap < 8) {
                const int dy1 = (tap + 1) / 3, dx1 = (tap + 1) % 3;
#pragma unroll
                for (int f = 0; f < 4; ++f)
                    pf[pn][f] = *reinterpret_cast<const bf16x8*>(
                        &sA[cc][row_l + dy1][f * 16 + l15 + dx1][quad][0]);
            } else if (cc < 3) {              // cc+1 tap0 (sA already valid)
#pragma unroll
                for (int f = 0; f < 4; ++f)
                    pf[pn][f] = *reinterpret_cast<const bf16x8*>(
                        &sA[cc + 1][row_l][f * 16 + l15][quad][0]);
            }
            // weight chain (tap8 -> next cc's tap0 by layout; cc3 tap8
            // overreads dead workspace past W2p — value unused)
            w[pn] = *reinterpret_cast<const bf16x8*>(
                wcc + (size_t)(tap + 1) * 2048);
            __builtin_amdgcn_sched_barrier(0);
#pragma unroll
            for (int f = 0; f < 4; ++f)
                acc[f] = __builtin_amdgcn_mfma_f32_16x16x32_bf16(
                    w[pb], pf[pb][f], acc[f], 0, 0, 0);
        }
    }

    // epilogue: bias + leaky -> bf16, hid2 pixel-major [g*4096+pix][64].
    // regs 0-3 consecutive oc -> one s16x4 store per f.
    const int prow = r0 + row_l;
    const size_t pixbase = (size_t)g * 4096 + (size_t)prow * 64;
    {
        const int ocb = ocq * 16 + quad * 4;
        const float4 bv4 = *reinterpret_cast<const float4*>(bias + g * 64 + ocb);
        const float bvv[4] = {bv4.x, bv4.y, bv4.z, bv4.w};
#pragma unroll
        for (int f = 0; f < 4; ++f) {
            s16x4 pkt;
#pragma unroll
            for (int reg = 0; reg < 4; ++reg) {
                float v = acc[f][reg] + bvv[reg];
                v = v >= 0.f ? v : 0.1f * v;
                pkt[reg] = f2bs(v);
            }
            *reinterpret_cast<s16x4*>(
                outp + (pixbase + f * 16 + l15) * 64 + ocb) = pkt;
        }
    }
}

// ---------------------------------------------------------------------------
// conv34_p2: FUSED conv3 (64->32, leaky) + conv4 (32->18 pad 32, linear).
// Round-9 verified, unchanged. hid3 stays in LDS.
// ---------------------------------------------------------------------------
__global__ __launch_bounds__(512, 2)
void conv34_p2(const short* __restrict__ hid2, const char* __restrict__ w3p,
               const char* __restrict__ w4p, const float* __restrict__ b3,
               const float* __restrict__ b4, float* __restrict__ oa)
{
    __shared__ __align__(16) short sA[6][2][66][4][8];   // 50688 B
    __shared__ __align__(16) short sH3[4][66][4][8];     // 16896 B

    const int b  = blockIdx.x;
    const int g  = b & 7;                     // XCD swizzle
    const int pt = b >> 3;                    // 0..31
    const int r0 = pt * 2;

    const int t    = threadIdx.x;
    const int wave = t >> 6, lane = t & 63;
    const int l15  = lane & 15, quad = lane >> 4;

    // conv3 mapping: hid3 row (0-3) x oc-half (0-1)
    const int wrow = wave & 3;
    const int och3 = wave >> 2;
    // conv4 mapping: out row (0-1) x oc-half (0-1) x px-half (0-1)
    const int w4row = wave & 1;
    const int och4  = (wave >> 1) & 1;
    const int pxh   = wave >> 2;

    // W3p [g][cc2][tap9][oc32][q4][ic8] (9216 shorts/block);
    // W4p [g][tap9][oc32][q4][ic8]
    const short* w3lane = (const short*)w3p + (size_t)(g * 2) * 9216
                        + ((size_t)(och3 * 16 + l15) * 4 + quad) * 8;
    const short* w4lane = (const short*)w4p + (size_t)g * 9216
                        + ((size_t)(och4 * 16 + l15) * 4 + quad) * 8;

    // ---- stage hid2 rows r0-2 .. r0+3 (waves 0-5; row = wave) ----
    if (wave < 6) {
        const int gy = r0 - 2 + wave;
        if (gy >= 0 && gy < 64) {
            const short* src = hid2 + ((size_t)g * 4096 + (size_t)gy * 64) * 64;
#pragma unroll
            for (int cc = 0; cc < 2; ++cc)
#pragma unroll
                for (int i = 0; i < 4; ++i)
                    gl_lds16(src + (size_t)(i * 16 + (lane >> 2)) * 64
                                 + cc * 32 + (lane & 3) * 8,
                             &sA[wave][cc][1 + i * 16][0][0]);
        } else {
            s16x4* rowdst = reinterpret_cast<s16x4*>(&sA[wave][0][0][0][0]);
            for (int i = lane; i < 1056; i += 64)
                rowdst[i] = s16x4{0, 0, 0, 0};
        }
    }
    // zero x-pad cols: sA (6r x 2cc x {0,65} x 4q = 96) + sH3 (4 x 2 x 4 = 32)
    if (t < 96) {
        int row = t / 16, cc = (t >> 3) & 1, col = (t & 4) ? 65 : 0, q = t & 3;
        *reinterpret_cast<bf16x8*>(&sA[row][cc][col][q][0]) =
            bf16x8{0, 0, 0, 0, 0, 0, 0, 0};
    } else if (t < 128) {
        int i = t - 96;
        int row = i >> 3, col = (i & 4) ? 65 : 0, q = i & 3;
        *reinterpret_cast<bf16x8*>(&sH3[row][col][q][0]) =
            bf16x8{0, 0, 0, 0, 0, 0, 0, 0};
    }

    // ---- conv3 ----
    bf16x8 w[2];
    bf16x8 pf[2][4];
    w[0] = *reinterpret_cast<const bf16x8*>(w3lane);   // cc0 tap0

    f32x4 acc3[4];
#pragma unroll
    for (int f = 0; f < 4; ++f)
#pragma unroll
        for (int r = 0; r < 4; ++r) acc3[f][r] = 0.f;

    __syncthreads();                          // staging + pads visible

#pragma unroll
    for (int cc = 0; cc < 2; ++cc) {
        const short* wcc = w3lane + (size_t)cc * 9216;
#pragma unroll
        for (int f = 0; f < 4; ++f)
            pf[0][f] = *reinterpret_cast<const bf16x8*>(
                &sA[wrow][cc][f * 16 + l15][quad][0]);
#pragma unroll
        for (int tap = 0; tap < 9; ++tap) {
            const int pb = tap & 1, pn = pb ^ 1;
            const int cb = (tap + cc) & 1, nb = cb ^ 1;
            if (tap < 8) {
                const int dy1 = (tap + 1) / 3, dx1 = (tap + 1) % 3;
#pragma unroll
                for (int f = 0; f < 4; ++f)
                    pf[pn][f] = *reinterpret_cast<const bf16x8*>(
                        &sA[wrow + dy1][cc][f * 16 + l15 + dx1][quad][0]);
            }
            // tap8 -> next cc's tap0 (block stride == 9*1024 shorts)
            w[nb] = *reinterpret_cast<const bf16x8*>(
                wcc + (size_t)(tap + 1) * 1024);
            __builtin_amdgcn_sched_barrier(0);
#pragma unroll
            for (int f = 0; f < 4; ++f)
                acc3[f] = __builtin_amdgcn_mfma_f32_16x16x32_bf16(
                    w[cb], pf[pb][f], acc3[f], 0, 0, 0);
        }
    }

    // hid3 -> sH3 (bias3 + leaky, bf16). OOB hid3 rows = zeros.
    {
        const int gy3 = r0 - 1 + wrow;
        const bool v3 = (gy3 >= 0 && gy3 < 64);
        const int qp = och3 * 2 + (quad >> 1);
        const int e0 = (quad & 1) * 4;
#pragma unroll
        for (int f = 0; f < 4; ++f) {
            s16x4 pkt;
#pragma unroll
            for (int reg = 0; reg < 4; ++reg) {
                const int oc3 = och3 * 16 + quad * 4 + reg;
                float v = acc3[f][reg] + b3[g * 32 + oc3];
                v = v >= 0.f ? v : 0.1f * v;
                pkt[reg] = v3 ? f2bs(v) : (short)0;
            }
            *reinterpret_cast<s16x4*>(&sH3[wrow][1 + f * 16 + l15][qp][e0]) = pkt;
        }
    }
    __syncthreads();                          // sH3 complete

    // ---- conv4 ----
    bf16x8 w4[2];
    bf16x8 pf4[2][2];
    w4[0] = *reinterpret_cast<const bf16x8*>(w4lane);

    f32x4 acc4[2];
#pragma unroll
    for (int f = 0; f < 2; ++f)
#pragma unroll
        for (int r = 0; r < 4; ++r) acc4[f][r] = 0.f;

#pragma unroll
    for (int f = 0; f < 2; ++f)
        pf4[0][f] = *reinterpret_cast<const bf16x8*>(
            &sH3[w4row][pxh * 32 + f * 16 + l15][quad][0]);
#pragma unroll
    for (int tap = 0; tap < 9; ++tap) {
        const int pb = tap & 1, pn = pb ^ 1;
        const int cb = tap & 1, nb = cb ^ 1;
        if (tap < 8) {
            const int dy1 = (tap + 1) / 3, dx1 = (tap + 1) % 3;
#pragma unroll
            for (int f = 0; f < 2; ++f)
                pf4[pn][f] = *reinterpret_cast<const bf16x8*>(
                    &sH3[w4row + dy1][pxh * 32 + f * 16 + l15 + dx1][quad][0]);
        }
        w4[nb] = *reinterpret_cast<const bf16x8*>(
            w4lane + (size_t)(tap + 1) * 1024);
        __builtin_amdgcn_sched_barrier(0);
#pragma unroll
        for (int f = 0; f < 2; ++f)
            acc4[f] = __builtin_amdgcn_mfma_f32_16x16x32_bf16(
                w4[cb], pf4[pb][f], acc4[f], 0, 0, 0);
    }

    // epilogue: bias4 (no leaky) -> oa fp32 [(g*18+oc)][4096]
    const int prow4 = r0 + w4row;
#pragma unroll
    for (int reg = 0; reg < 4; ++reg) {
        const int oc4 = och4 * 16 + quad * 4 + reg;
        if (oc4 < 18) {
            const float bv = b4[g * 18 + oc4];
#pragma unroll
            for (int f = 0; f < 2; ++f)
                oa[(size_t)(g * 18 + oc4) * HW + prow4 * 64 + pxh * 32
                   + f * 16 + l15] = acc4[f][reg] + bv;
        }
    }
}

// ---------------------------------------------------------------------------
// Fused softmax-over-groups + bilinear params + warp + combine (fp32 out).
// gar channels from gar_t pixel-major [4096][256]: one gather = 512 B
// contiguous per 32-lane group (4x128B lines).
// ---------------------------------------------------------------------------
__global__ __launch_bounds__(256)
void warp_combine_kernel(const float* __restrict__ oa,
                         const short* __restrict__ gar_t,
                         const float* __restrict__ mask,
                         float* __restrict__ out)
{
    __shared__ __align__(16) float4 sWts[8][6][8];
    __shared__ __align__(16) int4   sIdx[8][6][8];

    const int t = threadIdx.x;

    if (t < 48) {
        int lp = t / 6;
        int k  = t % 6;
        int p  = blockIdx.x * 8 + lp;
        int x  = p & 63, y = p >> 6;

        float l[8];
        float m = -1e30f;
#pragma unroll
        for (int g = 0; g < 8; ++g) {
            l[g] = oa[(size_t)(g * 18 + 12 + k) * HW + p];
            m = fmaxf(m, l[g]);
        }
        float s = 0.f;
#pragma unroll
        for (int g = 0; g < 8; ++g) { l[g] = __expf(l[g] - m); s += l[g]; }
        float inv = 1.f / s;

#pragma unroll
        for (int g = 0; g < 8; ++g) {
            float a  = l[g] * inv;
            float ox = oa[(size_t)(g * 18 + 2 * k)     * HW + p];
            float oy = oa[(size_t)(g * 18 + 2 * k + 1) * HW + p];
            float sx = fminf(fmaxf(((float)x + ox) * (64.f / 63.f) - 0.5f, 0.f), 63.f);
            float sy = fminf(fmaxf(((float)y + oy) * (64.f / 63.f) - 0.5f, 0.f), 63.f);
            float fx0 = floorf(sx), fy0 = floorf(sy);
            int   x0 = (int)fx0,    y0i = (int)fy0;
            float wx = sx - fx0,    wy = sy - fy0;
            int   x1 = min(x0 + 1, 63), y1 = min(y0i + 1, 63);
            sWts[lp][k][g] = make_float4(a * (1.f - wy) * (1.f - wx),
                                         a * (1.f - wy) * wx,
                                         a * wy * (1.f - wx),
                                         a * wy * wx);
            sIdx[lp][k][g] = make_int4(y0i * 64 + x0, y0i * 64 + x1,
                                       y1  * 64 + x0, y1  * 64 + x1);
        }
    }
    __syncthreads();

    const int lp = t >> 5;
    const int p  = blockIdx.x * 8 + lp;
    const int c0 = (t & 31) * 8;
    const short* ipc = gar_t + c0;            // pixel-major: row stride 256

    float acc[8];
#pragma unroll
    for (int j = 0; j < 8; ++j) acc[j] = 0.f;

    for (int g = 0; g < 8; ++g) {
        float4 m0 = *reinterpret_cast<const float4*>(mask + g * 256 + c0);
        float4 m1 = *reinterpret_cast<const float4*>(mask + g * 256 + c0 + 4);
        float mk[8] = {m0.x, m0.y, m0.z, m0.w, m1.x, m1.y, m1.z, m1.w};
#pragma unroll
        for (int k = 0; k < 6; ++k) {
            float4 w  = sWts[lp][k][g];
            int4   id = sIdx[lp][k][g];
            ushort8v v00 = *reinterpret_cast<const ushort8v*>(ipc + (size_t)id.x * 256);
            ushort8v v01 = *reinterpret_cast<const ushort8v*>(ipc + (size_t)id.y * 256);
            ushort8v v10 = *reinterpret_cast<const ushort8v*>(ipc + (size_t)id.z * 256);
            ushort8v v11 = *reinterpret_cast<const ushort8v*>(ipc + (size_t)id.w * 256);
#pragma unroll
            for (int j = 0; j < 8; ++j) {
                float sv = w.x * bfbits2f(v00[j]) + w.y * bfbits2f(v01[j])
                         + w.z * bfbits2f(v10[j]) + w.w * bfbits2f(v11[j]);
                acc[j] = fmaf(mk[j], sv, acc[j]);
            }
        }
    }
#pragma unroll
    for (int j = 0; j < 8; ++j)
        out[(size_t)(c0 + j) * HW + p] = acc[j];
}

// ---------------------------------------------------------------------------
// Workspace (~28 MB): inp_t 0-4M | W1p 4-9.2M (hid2 overlays dead W1p) |
// oa 10.5-12.9M | W2p 14M | W3p 15.5M | W4p 16M | hid1 17-25M |
// gar_t 26-28M. (hid3 eliminated by conv34 fusion.)
// ---------------------------------------------------------------------------
extern "C" void kernel_launch(void* const* d_in, const int* in_sizes, int n_in,
                              void* d_out, int out_size, void* d_ws, size_t ws_size,
                              hipStream_t stream)
{
    (void)in_sizes; (void)n_in; (void)out_size; (void)ws_size;
    const float* gar  = (const float*)d_in[0];
    const float* cond = (const float*)d_in[1];
    const float* mask = (const float*)d_in[2];
    const float* W1   = (const float*)d_in[3];
    const float* b1   = (const float*)d_in[4];
    const float* W2   = (const float*)d_in[5];
    const float* b2   = (const float*)d_in[6];
    const float* W3   = (const float*)d_in[7];
    const float* b3   = (const float*)d_in[8];
    const float* W4   = (const float*)d_in[9];
    const float* b4   = (const float*)d_in[10];
    float* out = (float*)d_out;

    char* ws = (char*)d_ws;
    short* inp_t  = (short*)(ws);
    char*  W1p    = ws + (4u << 20);
    short* hid2_t = (short*)(ws + (4u << 20));          // overlays dead W1p
    float* oa     = (float*)(ws + (10u << 20) + (512u << 10));
    char*  W2p    = ws + (14u << 20);
    char*  W3p    = ws + (15u << 20) + (512u << 10);
    char*  W4p    = ws + (16u << 20);
    short* hid1_t = (short*)(ws + (17u << 20));
    short* gar_t  = (short*)(ws + (26u << 20));

    // 312 weight-pack blocks + 2048 input-transpose blocks, one launch
    pack_all<<<2360, 256, 0, stream>>>(gar, cond, W1, W2, W3, W4,
                                       inp_t, gar_t, W1p, W2p, W3p, W4p);

    // conv1: round-10 verified structure + packed epilogue stores
    conv1_p2<<<512, 256, 0, stream>>>(inp_t, W1p, b1, hid1_t);
    // conv2: single-shot staging + packed epilogue stores
    conv2_ss<<<256, 512, 0, stream>>>(hid1_t, W2p, b2, hid2_t);
    // conv3+conv4 FUSED: hid3 stays in LDS; one dispatch fewer
    conv34_p2<<<256, 512, 0, stream>>>(hid2_t, W3p, W4p, b3, b4, oa);

    warp_combine_kernel<<<512, 256, 0, stream>>>(oa, gar_t, mask, out);
}

// Round 14
// 180.806 us; speedup vs baseline: 1.0498x; 1.0498x over previous
//
#include <hip/hip_runtime.h>
#include <hip/hip_bf16.h>

typedef __hip_bfloat16 bf16;
typedef unsigned short ushort8v __attribute__((ext_vector_type(8)));
typedef short  s16x4  __attribute__((ext_vector_type(4)));
typedef short  bf16x8 __attribute__((ext_vector_type(8)));   // 8 bf16 (4 VGPRs)
typedef float  f32x4  __attribute__((ext_vector_type(4)));

#define HW 4096
#define IMG_W 64

__device__ __forceinline__ float bfbits2f(unsigned short u) {
    return __uint_as_float(((unsigned int)u) << 16);
}
__device__ __forceinline__ short f2bs(float f) {
    bf16 h = __float2bfloat16(f);
    return *reinterpret_cast<short*>(&h);
}

// async global->LDS, 16B per lane. LDS dest = wave-uniform base + lane*16;
// the GLOBAL source address is per-lane (m173 pattern).
__device__ __forceinline__ void gl_lds16(const void* g, void* s) {
    __builtin_amdgcn_global_load_lds(
        (const __attribute__((address_space(1))) unsigned int*)g,
        (__attribute__((address_space(3))) unsigned int*)s, 16, 0, 0);
}

// ---------------------------------------------------------------------------
// pack_input: concat(gar,cond) fp32 [512][4096] -> inp_t bf16 chunked
// [cc=16][pix=4096][32ch] + gar_t bf16 pixel-major [4096][256].
// THIS ROUND (G13): float4 loads (16B/lane, was 4B scalar) and s16x4
// packed stores (8B, was 2B scalar) -> ~4x fewer memory instructions.
// Phase 1: thread (cg = t>>3, e4 = (t&7)*4) loads float4 of px e4..e4+3
// for channel cg into tile[cg][e4..]; phase 2: thread packs channels
// e4..e4+3 of px cg into one s16x4 (transpose via tile, stride 33).
// ---------------------------------------------------------------------------
__device__ void pack_input_dev(const float* __restrict__ gar,
                               const float* __restrict__ cond,
                               short* __restrict__ outp,
                               short* __restrict__ gart, int bx2, float* tile)
{
    int bx = bx2 & 127;                // px tile (128 tiles x 32 px)
    int by = bx2 >> 7;                 // ch tile (16) == cc chunk
    const int t  = threadIdx.x;
    const int cg = t >> 3;             // 0..31
    const int e4 = (t & 7) * 4;        // 0,4,..,28

    {
        int c = by * 32 + cg;          // branch block-uniform (by<8 <=> c<256)
        const float* src = (by < 8) ? (gar + (size_t)c * HW)
                                    : (cond + (size_t)(c - 256) * HW);
        float4 v = *reinterpret_cast<const float4*>(src + bx * 32 + e4);
        tile[cg * 33 + e4 + 0] = v.x;
        tile[cg * 33 + e4 + 1] = v.y;
        tile[cg * 33 + e4 + 2] = v.z;
        tile[cg * 33 + e4 + 3] = v.w;
    }
    __syncthreads();
    {
        int p = bx * 32 + cg;
        s16x4 pkt;
#pragma unroll
        for (int j = 0; j < 4; ++j)
            pkt[j] = f2bs(tile[(e4 + j) * 33 + cg]);
        *reinterpret_cast<s16x4*>(&outp[((size_t)by * 4096 + p) * 32 + e4]) = pkt;
        if (by < 8)                    // gar channels only (block-uniform)
            *reinterpret_cast<s16x4*>(&gart[(size_t)p * 256 + by * 32 + e4]) = pkt;
    }
}

// ---------------------------------------------------------------------------
// pack_w: W fp32 [G][CREAL][CIN][3][3] -> bf16 blocks, COAL layout
// [g][nt][cc][tap 9][oc BN][q 4][8 ic]. THIS ROUND (G13): float4 weight
// loads (4 consecutive r within one oc; all strides 16B-aligned since
// CIN*9*4 is a multiple of 16 for CIN in {512,128,64,32}) + 16B LDS
// zero/copy loops. BLKB = 9*4*BN*16 bytes.
// ---------------------------------------------------------------------------
template<int CIN, int CREAL, int BN, int NT, bool COAL>
__device__ void pack_w_dev(const float* __restrict__ wgt, char* __restrict__ wp,
                           int bx, short* sT)
{
    constexpr int NCC  = CIN / 32;
    constexpr int BLKB = 9 * 4 * BN * 16;

    const int t  = threadIdx.x;
    const int cc = bx % NCC;
    const int nt = (bx / NCC) % NT;
    const int g  = bx / (NT * NCC);

    for (int i = t; i < BLKB / 16; i += 256)
        reinterpret_cast<bf16x8*>(sT)[i] = bf16x8{0, 0, 0, 0, 0, 0, 0, 0};
    __syncthreads();

    int ocmax = CREAL - nt * BN; if (ocmax > BN) ocmax = BN;
    const size_t base = ((size_t)(g * CREAL + nt * BN) * CIN + cc * 32) * 9;
    for (int i4 = t * 4; i4 < ocmax * 288; i4 += 1024) {
        int oc = i4 / 288;
        int r  = i4 % 288;                     // ic*9 + tap; 4-block stays in oc
        float4 wv = *reinterpret_cast<const float4*>(
            &wgt[base + (size_t)oc * CIN * 9 + r]);
        float wa[4] = {wv.x, wv.y, wv.z, wv.w};
#pragma unroll
        for (int j = 0; j < 4; ++j) {
            int rr = r + j;
            int ic = rr / 9, tap = rr % 9;
            size_t idx;
            if (COAL) idx = (size_t)(((tap * BN + oc) * 4 + (ic >> 3)) * 8 + (ic & 7));
            else      idx = (size_t)(((tap * 4 + (ic >> 3)) * BN + oc) * 8 + (ic & 7));
            sT[idx] = f2bs(wa[j]);
        }
    }
    __syncthreads();

    const bf16x8* src = reinterpret_cast<const bf16x8*>(sT);
    bf16x8* dst = reinterpret_cast<bf16x8*>(wp + (size_t)bx * BLKB);
    for (int i = t; i < BLKB / 16; i += 256)
        dst[i] = src[i];
}

// All packing in one launch (block-range dispatch; branch is block-uniform).
__global__ __launch_bounds__(256)
void pack_all(const float* __restrict__ gar, const float* __restrict__ cond,
              const float* __restrict__ W1, const float* __restrict__ W2,
              const float* __restrict__ W3, const float* __restrict__ W4,
              short* inp_t, short* gar_t,
              char* W1p, char* W2p, char* W3p, char* W4p)
{
    __shared__ __align__(16) short sbuf[9 * 4 * 64 * 8];   // 36864 B
    int bx = blockIdx.x;
    if (bx < 256)      pack_w_dev<512, 128, 64, 2, true>(W1, W1p, bx,       sbuf);
    else if (bx < 288) pack_w_dev<128,  64, 64, 1, true>(W2, W2p, bx - 256, sbuf);
    else if (bx < 304) pack_w_dev< 64,  32, 32, 1, true>(W3, W3p, bx - 288, sbuf);
    else if (bx < 312) pack_w_dev< 32,  18, 32, 1, true>(W4, W4p, bx - 304, sbuf);
    else pack_input_dev(gar, cond, inp_t, gar_t, bx - 312, (float*)sbuf);
}

// ---------------------------------------------------------------------------
// conv1_p2: dual-stream register pipeline, full-K, 2 blocks/CU (512 x 256).
// Round-10/13 verified (~48.5-49.3us). UNCHANGED.
// ---------------------------------------------------------------------------
__global__ __launch_bounds__(256, 2)
void conv1_p2(const short* __restrict__ inp, const char* __restrict__ wp,
              const float* __restrict__ bias, short* __restrict__ outp)
{
    __shared__ __align__(16) short sA[2][4][66][4][8];   // 33792 B

    const int b  = blockIdx.x;
    const int g  = b & 7;                     // XCD swizzle: group per XCD
    const int r_ = b >> 3;
    const int pt = r_ & 31;                   // 0..31
    const int nt = r_ >> 5;                   // oc 64-half (0-1)
    const int r0 = pt * 2;

    const int t    = threadIdx.x;
    const int wave = t >> 6, lane = t & 63;
    const int l15  = lane & 15, quad = lane >> 4;

    const int row_l = wave & 1;               // px row (0-1)
    const int ocw   = (wave >> 1) * 32;       // oc 32-group within nt

    // W1p layout [g][nt][cc 16][tap 9][oc 64][q 4][ic 8]
    const short* wb    = (const short*)wp + (size_t)(g * 2 + nt) * 16 * 18432;
    const short* wlane = wb + ((size_t)(ocw + l15) * 4 + quad) * 8;

    // staging: wave w stages halo row w (4 x 1KB DMA)
    auto stageDMA = [&](int cc, int buf) {
        const int gy = r0 - 1 + wave;
        if (gy >= 0 && gy < 64) {
            const short* src = inp + ((size_t)cc * 4096 + (size_t)gy * 64) * 32
                                   + (size_t)lane * 8;
#pragma unroll
            for (int c4 = 0; c4 < 4; ++c4)
                gl_lds16(src + c4 * 512, &sA[buf][wave][1 + c4 * 16][0][0]);
        }
    };

    f32x4 acc[2][4];
#pragma unroll
    for (int o = 0; o < 2; ++o)
#pragma unroll
        for (int f = 0; f < 4; ++f)
#pragma unroll
            for (int r = 0; r < 4; ++r) acc[o][f][r] = 0.f;

    // prologue: DMA(0) into buf0, zero x-pads (both bufs) + OOB rows
    stageDMA(0, 0);
    if (t < 64) {
        int buf = t >> 5, row = (t >> 3) & 3, q = (t >> 1) & 3;
        int col = (t & 1) ? 65 : 0;
        *reinterpret_cast<bf16x8*>(&sA[buf][row][col][q][0]) =
            bf16x8{0, 0, 0, 0, 0, 0, 0, 0};
    }
    if (r0 == 0 || r0 == 62) {
        int zr = (r0 == 0) ? 0 : 3;           // gy=-1 or gy=64: zero forever
        for (int i = t; i < 2 * 66 * 4; i += 256) {
            int buf = i / 264, rem = i % 264;
            *reinterpret_cast<bf16x8*>(&sA[buf][zr][rem >> 2][rem & 3][0]) =
                bf16x8{0, 0, 0, 0, 0, 0, 0, 0};
        }
    }

    // weight double-buffer (16 VGPR) + pF double-buffer (32 VGPR)
    bf16x8 w[2][2];
    bf16x8 pf[2][4];
#pragma unroll
    for (int o = 0; o < 2; ++o)               // cc0 tap0 weights -> w[0]
        w[0][o] = *reinterpret_cast<const bf16x8*>(wlane + o * 512);

    auto body = [&](int cc, int cur, int par) {
        const short* wcc = wlane + (size_t)cc * 18432;
        __syncthreads();                      // sA[cur] published (DMA drained)
        if (cc + 1 < 16) stageDMA(cc + 1, cur ^ 1);
        // prime tap0 pF
#pragma unroll
        for (int f = 0; f < 4; ++f)
            pf[0][f] = *reinterpret_cast<const bf16x8*>(
                &sA[cur][row_l][f * 16 + l15][quad][0]);
#pragma unroll
        for (int tap = 0; tap < 9; ++tap) {
            const int pb = tap & 1, pn = pb ^ 1;
            const int cb = (tap + par) & 1, nb = cb ^ 1;
            // prefetch next tap's pF (taps 0-7)
            if (tap < 8) {
                const int dy1 = (tap + 1) / 3, dx1 = (tap + 1) % 3;
#pragma unroll
                for (int f = 0; f < 4; ++f)
                    pf[pn][f] = *reinterpret_cast<const bf16x8*>(
                        &sA[cur][row_l + dy1][f * 16 + l15 + dx1][quad][0]);
            }
            // prefetch next tap's weights (tap8 -> next cc's tap0 by layout)
            const short* nsrc = wcc + (size_t)(tap + 1) * 2048;
#pragma unroll
            for (int o = 0; o < 2; ++o)
                w[nb][o] = *reinterpret_cast<const bf16x8*>(nsrc + o * 512);
            __builtin_amdgcn_sched_barrier(0);   // pin both streams pre-MFMA
#pragma unroll
            for (int o = 0; o < 2; ++o)
#pragma unroll
                for (int f = 0; f < 4; ++f)
                    acc[o][f] = __builtin_amdgcn_mfma_f32_16x16x32_bf16(
                        w[cb][o], pf[pb][f], acc[o][f], 0, 0, 0);
        }
    };

    for (int c2 = 0; c2 < 16; c2 += 2) {
        body(c2,     0, 0);
        body(c2 + 1, 1, 1);
    }

    // epilogue: bias + leaky -> bf16, out [pix][128]. m(oc)=quad*4+reg.
    const int prow = r0 + row_l;
    const size_t pixbase = (size_t)g * 4096 + (size_t)prow * 64;
#pragma unroll
    for (int o = 0; o < 2; ++o) {
        const int ocb = nt * 64 + ocw + o * 16 + quad * 4;
        const float4 bv4 = *reinterpret_cast<const float4*>(bias + g * 128 + ocb);
        const float bvv[4] = {bv4.x, bv4.y, bv4.z, bv4.w};
#pragma unroll
        for (int f = 0; f < 4; ++f) {
            s16x4 pkt;
#pragma unroll
            for (int reg = 0; reg < 4; ++reg) {
                float v = acc[o][f][reg] + bvv[reg];
                v = v >= 0.f ? v : 0.1f * v;
                pkt[reg] = f2bs(v);
            }
            *reinterpret_cast<s16x4*>(
                outp + (pixbase + f * 16 + l15) * 128 + ocb) = pkt;
        }
    }
}

// ---------------------------------------------------------------------------
// conv2_ss: single-shot staging, one barrier, continuous 36-tap pipeline.
// Round-12/13 verified. UNCHANGED.
// ---------------------------------------------------------------------------
__global__ __launch_bounds__(512, 2)
void conv2_ss(const short* __restrict__ inp, const char* __restrict__ wp,
              const float* __restrict__ bias, short* __restrict__ outp)
{
    __shared__ __align__(16) short sA[4][4][66][4][8];   // 67584 B

    const int b  = blockIdx.x;
    const int g  = b & 7;
    const int pt = b >> 3;                    // 0..31
    const int r0 = pt * 2;

    const int t    = threadIdx.x;
    const int wave = t >> 6, lane = t & 63;
    const int l15  = lane & 15, quad = lane >> 4;

    const int row_l = wave & 1;               // px row (0-1)
    const int ocq   = wave >> 1;              // oc 16-group (0-3)

    // W2p layout [g][cc 4][tap 9][oc 64][q 4][ic 8]
    const short* wb    = (const short*)wp + (size_t)g * 4 * 18432;
    const short* wlane = wb + ((size_t)(ocq * 16 + l15) * 4 + quad) * 8;

    // ---- stage ALL 4 cc: 16 (cc,row) units; wave w -> units 2w, 2w+1 ----
#pragma unroll
    for (int s = 0; s < 2; ++s) {
        const int u   = wave * 2 + s;
        const int cc  = u >> 2, row = u & 3;
        const int gy  = r0 - 1 + row;
        if (gy >= 0 && gy < 64) {
            const short* rowb = inp + ((size_t)g * 4096 + (size_t)gy * 64) * 128
                                    + cc * 32 + (lane & 3) * 8;
#pragma unroll
            for (int i = 0; i < 4; ++i)
                gl_lds16(rowb + (size_t)(i * 16 + (lane >> 2)) * 128,
                         &sA[cc][row][1 + i * 16][0][0]);
        }
    }
    // x-pad zero: 4cc x 4row x {0,65} x 4q = 128 units
    if (t < 128) {
        int cc = t >> 5, row = (t >> 3) & 3, col = (t & 4) ? 65 : 0, q = t & 3;
        *reinterpret_cast<bf16x8*>(&sA[cc][row][col][q][0]) =
            bf16x8{0, 0, 0, 0, 0, 0, 0, 0};
    }
    if (r0 == 0 || r0 == 62) {
        int zr = (r0 == 0) ? 0 : 3;           // gy=-1 or gy=64 row: zeros
        for (int i = t; i < 4 * 264; i += 512) {
            int cc = i / 264, rem = i % 264;
            *reinterpret_cast<bf16x8*>(&sA[cc][zr][rem >> 2][rem & 3][0]) =
                bf16x8{0, 0, 0, 0, 0, 0, 0, 0};
        }
    }

    f32x4 acc[4];
#pragma unroll
    for (int f = 0; f < 4; ++f)
#pragma unroll
        for (int r = 0; r < 4; ++r) acc[f][r] = 0.f;

    bf16x8 w[2];
    bf16x8 pf[2][4];
    w[0] = *reinterpret_cast<const bf16x8*>(wlane);    // cc0 tap0 weights

    __syncthreads();   // the ONLY barrier: all staging drained & visible

    // prime cc0 tap0 pF
#pragma unroll
    for (int f = 0; f < 4; ++f)
        pf[0][f] = *reinterpret_cast<const bf16x8*>(
            &sA[0][row_l][f * 16 + l15][quad][0]);

#pragma unroll
    for (int cc = 0; cc < 4; ++cc) {
        const short* wcc = wlane + (size_t)cc * 18432;
#pragma unroll
        for (int tap = 0; tap < 9; ++tap) {
            const int pb = (cc + tap) & 1, pn = pb ^ 1;  // shared parity
            // prefetch next global tap's pF
            if (tap < 8) {
                const int dy1 = (tap + 1) / 3, dx1 = (tap + 1) % 3;
#pragma unroll
                for (int f = 0; f < 4; ++f)
                    pf[pn][f] = *reinterpret_cast<const bf16x8*>(
                        &sA[cc][row_l + dy1][f * 16 + l15 + dx1][quad][0]);
            } else if (cc < 3) {              // cc+1 tap0 (sA already valid)
#pragma unroll
                for (int f = 0; f < 4; ++f)
                    pf[pn][f] = *reinterpret_cast<const bf16x8*>(
                        &sA[cc + 1][row_l][f * 16 + l15][quad][0]);
            }
            // weight chain (tap8 -> next cc's tap0 by layout; cc3 tap8
            // overreads dead workspace past W2p — value unused)
            w[pn] = *reinterpret_cast<const bf16x8*>(
                wcc + (size_t)(tap + 1) * 2048);
            __builtin_amdgcn_sched_barrier(0);
#pragma unroll
            for (int f = 0; f < 4; ++f)
                acc[f] = __builtin_amdgcn_mfma_f32_16x16x32_bf16(
                    w[pb], pf[pb][f], acc[f], 0, 0, 0);
        }
    }

    // epilogue: bias + leaky -> bf16, hid2 pixel-major [g*4096+pix][64].
    const int prow = r0 + row_l;
    const size_t pixbase = (size_t)g * 4096 + (size_t)prow * 64;
    {
        const int ocb = ocq * 16 + quad * 4;
        const float4 bv4 = *reinterpret_cast<const float4*>(bias + g * 64 + ocb);
        const float bvv[4] = {bv4.x, bv4.y, bv4.z, bv4.w};
#pragma unroll
        for (int f = 0; f < 4; ++f) {
            s16x4 pkt;
#pragma unroll
            for (int reg = 0; reg < 4; ++reg) {
                float v = acc[f][reg] + bvv[reg];
                v = v >= 0.f ? v : 0.1f * v;
                pkt[reg] = f2bs(v);
            }
            *reinterpret_cast<s16x4*>(
                outp + (pixbase + f * 16 + l15) * 64 + ocb) = pkt;
        }
    }
}

// ---------------------------------------------------------------------------
// conv34_p2: FUSED conv3 (64->32, leaky) + conv4 (32->18 pad 32, linear).
// Round-9 verified, unchanged. hid3 stays in LDS.
// ---------------------------------------------------------------------------
__global__ __launch_bounds__(512, 2)
void conv34_p2(const short* __restrict__ hid2, const char* __restrict__ w3p,
               const char* __restrict__ w4p, const float* __restrict__ b3,
               const float* __restrict__ b4, float* __restrict__ oa)
{
    __shared__ __align__(16) short sA[6][2][66][4][8];   // 50688 B
    __shared__ __align__(16) short sH3[4][66][4][8];     // 16896 B

    const int b  = blockIdx.x;
    const int g  = b & 7;                     // XCD swizzle
    const int pt = b >> 3;                    // 0..31
    const int r0 = pt * 2;

    const int t    = threadIdx.x;
    const int wave = t >> 6, lane = t & 63;
    const int l15  = lane & 15, quad = lane >> 4;

    // conv3 mapping: hid3 row (0-3) x oc-half (0-1)
    const int wrow = wave & 3;
    const int och3 = wave >> 2;
    // conv4 mapping: out row (0-1) x oc-half (0-1) x px-half (0-1)
    const int w4row = wave & 1;
    const int och4  = (wave >> 1) & 1;
    const int pxh   = wave >> 2;

    // W3p [g][cc2][tap9][oc32][q4][ic8] (9216 shorts/block);
    // W4p [g][tap9][oc32][q4][ic8]
    const short* w3lane = (const short*)w3p + (size_t)(g * 2) * 9216
                        + ((size_t)(och3 * 16 + l15) * 4 + quad) * 8;
    const short* w4lane = (const short*)w4p + (size_t)g * 9216
                        + ((size_t)(och4 * 16 + l15) * 4 + quad) * 8;

    // ---- stage hid2 rows r0-2 .. r0+3 (waves 0-5; row = wave) ----
    if (wave < 6) {
        const int gy = r0 - 2 + wave;
        if (gy >= 0 && gy < 64) {
            const short* src = hid2 + ((size_t)g * 4096 + (size_t)gy * 64) * 64;
#pragma unroll
            for (int cc = 0; cc < 2; ++cc)
#pragma unroll
                for (int i = 0; i < 4; ++i)
                    gl_lds16(src + (size_t)(i * 16 + (lane >> 2)) * 64
                                 + cc * 32 + (lane & 3) * 8,
                             &sA[wave][cc][1 + i * 16][0][0]);
        } else {
            s16x4* rowdst = reinterpret_cast<s16x4*>(&sA[wave][0][0][0][0]);
            for (int i = lane; i < 1056; i += 64)
                rowdst[i] = s16x4{0, 0, 0, 0};
        }
    }
    // zero x-pad cols: sA (6r x 2cc x {0,65} x 4q = 96) + sH3 (4 x 2 x 4 = 32)
    if (t < 96) {
        int row = t / 16, cc = (t >> 3) & 1, col = (t & 4) ? 65 : 0, q = t & 3;
        *reinterpret_cast<bf16x8*>(&sA[row][cc][col][q][0]) =
            bf16x8{0, 0, 0, 0, 0, 0, 0, 0};
    } else if (t < 128) {
        int i = t - 96;
        int row = i >> 3, col = (i & 4) ? 65 : 0, q = i & 3;
        *reinterpret_cast<bf16x8*>(&sH3[row][col][q][0]) =
            bf16x8{0, 0, 0, 0, 0, 0, 0, 0};
    }

    // ---- conv3 ----
    bf16x8 w[2];
    bf16x8 pf[2][4];
    w[0] = *reinterpret_cast<const bf16x8*>(w3lane);   // cc0 tap0

    f32x4 acc3[4];
#pragma unroll
    for (int f = 0; f < 4; ++f)
#pragma unroll
        for (int r = 0; r < 4; ++r) acc3[f][r] = 0.f;

    __syncthreads();                          // staging + pads visible

#pragma unroll
    for (int cc = 0; cc < 2; ++cc) {
        const short* wcc = w3lane + (size_t)cc * 9216;
#pragma unroll
        for (int f = 0; f < 4; ++f)
            pf[0][f] = *reinterpret_cast<const bf16x8*>(
                &sA[wrow][cc][f * 16 + l15][quad][0]);
#pragma unroll
        for (int tap = 0; tap < 9; ++tap) {
            const int pb = tap & 1, pn = pb ^ 1;
            const int cb = (tap + cc) & 1, nb = cb ^ 1;
            if (tap < 8) {
                const int dy1 = (tap + 1) / 3, dx1 = (tap + 1) % 3;
#pragma unroll
                for (int f = 0; f < 4; ++f)
                    pf[pn][f] = *reinterpret_cast<const bf16x8*>(
                        &sA[wrow + dy1][cc][f * 16 + l15 + dx1][quad][0]);
            }
            // tap8 -> next cc's tap0 (block stride == 9*1024 shorts)
            w[nb] = *reinterpret_cast<const bf16x8*>(
                wcc + (size_t)(tap + 1) * 1024);
            __builtin_amdgcn_sched_barrier(0);
#pragma unroll
            for (int f = 0; f < 4; ++f)
                acc3[f] = __builtin_amdgcn_mfma_f32_16x16x32_bf16(
                    w[cb], pf[pb][f], acc3[f], 0, 0, 0);
        }
    }

    // hid3 -> sH3 (bias3 + leaky, bf16). OOB hid3 rows = zeros.
    {
        const int gy3 = r0 - 1 + wrow;
        const bool v3 = (gy3 >= 0 && gy3 < 64);
        const int qp = och3 * 2 + (quad >> 1);
        const int e0 = (quad & 1) * 4;
#pragma unroll
        for (int f = 0; f < 4; ++f) {
            s16x4 pkt;
#pragma unroll
            for (int reg = 0; reg < 4; ++reg) {
                const int oc3 = och3 * 16 + quad * 4 + reg;
                float v = acc3[f][reg] + b3[g * 32 + oc3];
                v = v >= 0.f ? v : 0.1f * v;
                pkt[reg] = v3 ? f2bs(v) : (short)0;
            }
            *reinterpret_cast<s16x4*>(&sH3[wrow][1 + f * 16 + l15][qp][e0]) = pkt;
        }
    }
    __syncthreads();                          // sH3 complete

    // ---- conv4 ----
    bf16x8 w4[2];
    bf16x8 pf4[2][2];
    w4[0] = *reinterpret_cast<const bf16x8*>(w4lane);

    f32x4 acc4[2];
#pragma unroll
    for (int f = 0; f < 2; ++f)
#pragma unroll
        for (int r = 0; r < 4; ++r) acc4[f][r] = 0.f;

#pragma unroll
    for (int f = 0; f < 2; ++f)
        pf4[0][f] = *reinterpret_cast<const bf16x8*>(
            &sH3[w4row][pxh * 32 + f * 16 + l15][quad][0]);
#pragma unroll
    for (int tap = 0; tap < 9; ++tap) {
        const int pb = tap & 1, pn = pb ^ 1;
        const int cb = tap & 1, nb = cb ^ 1;
        if (tap < 8) {
            const int dy1 = (tap + 1) / 3, dx1 = (tap + 1) % 3;
#pragma unroll
            for (int f = 0; f < 2; ++f)
                pf4[pn][f] = *reinterpret_cast<const bf16x8*>(
                    &sH3[w4row + dy1][pxh * 32 + f * 16 + l15 + dx1][quad][0]);
        }
        w4[nb] = *reinterpret_cast<const bf16x8*>(
            w4lane + (size_t)(tap + 1) * 1024);
        __builtin_amdgcn_sched_barrier(0);
#pragma unroll
        for (int f = 0; f < 2; ++f)
            acc4[f] = __builtin_amdgcn_mfma_f32_16x16x32_bf16(
                w4[cb], pf4[pb][f], acc4[f], 0, 0, 0);
    }

    // epilogue: bias4 (no leaky) -> oa fp32 [(g*18+oc)][4096]
    const int prow4 = r0 + w4row;
#pragma unroll
    for (int reg = 0; reg < 4; ++reg) {
        const int oc4 = och4 * 16 + quad * 4 + reg;
        if (oc4 < 18) {
            const float bv = b4[g * 18 + oc4];
#pragma unroll
            for (int f = 0; f < 2; ++f)
                oa[(size_t)(g * 18 + oc4) * HW + prow4 * 64 + pxh * 32
                   + f * 16 + l15] = acc4[f][reg] + bv;
        }
    }
}

// ---------------------------------------------------------------------------
// Fused softmax-over-groups + bilinear params + warp + combine (fp32 out).
// THIS ROUND: setup parallelized over all 384 (lp,k,g) items (256 threads,
// 1.5 rounds) instead of 48 threads x 8-deep serial loops; softmax max/sum
// via 8-lane __shfl_xor tree (items of one (lp,k) group sit on 8
// consecutive lanes by construction: i = (lp*6+k)*8 + g, both rounds).
// Gather phase unchanged (gar_t pixel-major, 512B contiguous per group).
// ---------------------------------------------------------------------------
__global__ __launch_bounds__(256)
void warp_combine_kernel(const float* __restrict__ oa,
                         const short* __restrict__ gar_t,
                         const float* __restrict__ mask,
                         float* __restrict__ out)
{
    __shared__ __align__(16) float4 sWts[8][6][8];
    __shared__ __align__(16) int4   sIdx[8][6][8];

    const int t = threadIdx.x;

    auto do_item = [&](int i) {
        const int lp  = i / 48;
        const int rem = i - lp * 48;
        const int k   = rem >> 3;
        const int g   = rem & 7;
        const int p   = blockIdx.x * 8 + lp;
        const int x   = p & 63, y = p >> 6;

        float lg = oa[(size_t)(g * 18 + 12 + k) * HW + p];
        float m = lg;
        m = fmaxf(m, __shfl_xor(m, 1));
        m = fmaxf(m, __shfl_xor(m, 2));
        m = fmaxf(m, __shfl_xor(m, 4));
        float e = __expf(lg - m);
        float s = e;
        s += __shfl_xor(s, 1);
        s += __shfl_xor(s, 2);
        s += __shfl_xor(s, 4);
        float a = e / s;

        float ox = oa[(size_t)(g * 18 + 2 * k)     * HW + p];
        float oy = oa[(size_t)(g * 18 + 2 * k + 1) * HW + p];
        float sx = fminf(fmaxf(((float)x + ox) * (64.f / 63.f) - 0.5f, 0.f), 63.f);
        float sy = fminf(fmaxf(((float)y + oy) * (64.f / 63.f) - 0.5f, 0.f), 63.f);
        float fx0 = floorf(sx), fy0 = floorf(sy);
        int   x0 = (int)fx0,    y0i = (int)fy0;
        float wx = sx - fx0,    wy = sy - fy0;
        int   x1 = min(x0 + 1, 63), y1 = min(y0i + 1, 63);
        sWts[lp][k][g] = make_float4(a * (1.f - wy) * (1.f - wx),
                                     a * (1.f - wy) * wx,
                                     a * wy * (1.f - wx),
                                     a * wy * wx);
        sIdx[lp][k][g] = make_int4(y0i * 64 + x0, y0i * 64 + x1,
                                   y1  * 64 + x0, y1  * 64 + x1);
    };

    do_item(t);                 // items 0..255 (all waves fully active)
    if (t < 128) do_item(256 + t);   // items 256..383 (waves 0-1 full)
    __syncthreads();

    const int lp = t >> 5;
    const int p  = blockIdx.x * 8 + lp;
    const int c0 = (t & 31) * 8;
    const short* ipc = gar_t + c0;            // pixel-major: row stride 256

    float acc[8];
#pragma unroll
    for (int j = 0; j < 8; ++j) acc[j] = 0.f;

    for (int g = 0; g < 8; ++g) {
        float4 m0 = *reinterpret_cast<const float4*>(mask + g * 256 + c0);
        float4 m1 = *reinterpret_cast<const float4*>(mask + g * 256 + c0 + 4);
        float mk[8] = {m0.x, m0.y, m0.z, m0.w, m1.x, m1.y, m1.z, m1.w};
#pragma unroll
        for (int k = 0; k < 6; ++k) {
            float4 w  = sWts[lp][k][g];
            int4   id = sIdx[lp][k][g];
            ushort8v v00 = *reinterpret_cast<const ushort8v*>(ipc + (size_t)id.x * 256);
            ushort8v v01 = *reinterpret_cast<const ushort8v*>(ipc + (size_t)id.y * 256);
            ushort8v v10 = *reinterpret_cast<const ushort8v*>(ipc + (size_t)id.z * 256);
            ushort8v v11 = *reinterpret_cast<const ushort8v*>(ipc + (size_t)id.w * 256);
#pragma unroll
            for (int j = 0; j < 8; ++j) {
                float sv = w.x * bfbits2f(v00[j]) + w.y * bfbits2f(v01[j])
                         + w.z * bfbits2f(v10[j]) + w.w * bfbits2f(v11[j]);
                acc[j] = fmaf(mk[j], sv, acc[j]);
            }
        }
    }
#pragma unroll
    for (int j = 0; j < 8; ++j)
        out[(size_t)(c0 + j) * HW + p] = acc[j];
}

// ---------------------------------------------------------------------------
// Workspace (~28 MB): inp_t 0-4M | W1p 4-9.2M (hid2 overlays dead W1p) |
// oa 10.5-12.9M | W2p 14M | W3p 15.5M | W4p 16M | hid1 17-25M |
// gar_t 26-28M. (hid3 eliminated by conv34 fusion.)
// ---------------------------------------------------------------------------
extern "C" void kernel_launch(void* const* d_in, const int* in_sizes, int n_in,
                              void* d_out, int out_size, void* d_ws, size_t ws_size,
                              hipStream_t stream)
{
    (void)in_sizes; (void)n_in; (void)out_size; (void)ws_size;
    const float* gar  = (const float*)d_in[0];
    const float* cond = (const float*)d_in[1];
    const float* mask = (const float*)d_in[2];
    const float* W1   = (const float*)d_in[3];
    const float* b1   = (const float*)d_in[4];
    const float* W2   = (const float*)d_in[5];
    const float* b2   = (const float*)d_in[6];
    const float* W3   = (const float*)d_in[7];
    const float* b3   = (const float*)d_in[8];
    const float* W4   = (const float*)d_in[9];
    const float* b4   = (const float*)d_in[10];
    float* out = (float*)d_out;

    char* ws = (char*)d_ws;
    short* inp_t  = (short*)(ws);
    char*  W1p    = ws + (4u << 20);
    short* hid2_t = (short*)(ws + (4u << 20));          // overlays dead W1p
    float* oa     = (float*)(ws + (10u << 20) + (512u << 10));
    char*  W2p    = ws + (14u << 20);
    char*  W3p    = ws + (15u << 20) + (512u << 10);
    char*  W4p    = ws + (16u << 20);
    short* hid1_t = (short*)(ws + (17u << 20));
    short* gar_t  = (short*)(ws + (26u << 20));

    // 312 weight-pack blocks + 2048 input-transpose blocks, one launch
    pack_all<<<2360, 256, 0, stream>>>(gar, cond, W1, W2, W3, W4,
                                       inp_t, gar_t, W1p, W2p, W3p, W4p);

    // conv1: round-10 verified structure (unchanged)
    conv1_p2<<<512, 256, 0, stream>>>(inp_t, W1p, b1, hid1_t);
    // conv2: single-shot staging (unchanged)
    conv2_ss<<<256, 512, 0, stream>>>(hid1_t, W2p, b2, hid2_t);
    // conv3+conv4 FUSED (unchanged)
    conv34_p2<<<256, 512, 0, stream>>>(hid2_t, W3p, W4p, b3, b4, oa);

    warp_combine_kernel<<<512, 256, 0, stream>>>(oa, gar_t, mask, out);
}